// Round 1
// baseline (2763.895 us; speedup 1.0000x reference)
//
#include <hip/hip_runtime.h>

#define IN_F 256
#define OUT_F 128

// ---------------- K1: support = x @ W  (fp32, register-blocked) -------------
// 16 rows per block, 256 threads: thread (c = t&127, rbase = (t>>7)*8) computes
// 8 outputs. x rows staged in LDS (16 KB); W streamed from L2 (128 KB total,
// each element reused across 16 rows per block).
__global__ __launch_bounds__(256) void gemm_xw(const float* __restrict__ x,
                                               const float* __restrict__ w,
                                               float* __restrict__ sup,
                                               int n_nodes) {
  __shared__ float xs[16][IN_F];
  int row0 = blockIdx.x * 16;
  // stage 16 rows x 256 f32 = 4096 floats = 1024 float4, 256 threads x 4
  const float4* xg = (const float4*)(x + (size_t)row0 * IN_F);
  float4* xsv = (float4*)&xs[0][0];
#pragma unroll
  for (int i = 0; i < 4; ++i) xsv[threadIdx.x + i * 256] = xg[threadIdx.x + i * 256];
  __syncthreads();

  int c = threadIdx.x & 127;
  int rbase = (threadIdx.x >> 7) * 8;
  float acc[8] = {0.f, 0.f, 0.f, 0.f, 0.f, 0.f, 0.f, 0.f};
  for (int k = 0; k < IN_F; k += 4) {
    float w0 = w[(k + 0) * OUT_F + c];
    float w1 = w[(k + 1) * OUT_F + c];
    float w2 = w[(k + 2) * OUT_F + c];
    float w3 = w[(k + 3) * OUT_F + c];
#pragma unroll
    for (int r = 0; r < 8; ++r) {
      float4 xv = *(const float4*)&xs[rbase + r][k];  // broadcast ds_read_b128
      acc[r] = fmaf(xv.x, w0, acc[r]);
      acc[r] = fmaf(xv.y, w1, acc[r]);
      acc[r] = fmaf(xv.z, w2, acc[r]);
      acc[r] = fmaf(xv.w, w3, acc[r]);
    }
  }
#pragma unroll
  for (int r = 0; r < 8; ++r) {
    int row = row0 + rbase + r;
    if (row < n_nodes) sup[(size_t)row * OUT_F + c] = acc[r];
  }
}

// ---------------- K2: out[n][c] = bias[c] ----------------------------------
__global__ __launch_bounds__(256) void init_bias(float* __restrict__ out,
                                                 const float* __restrict__ bias,
                                                 int total) {
  int i = blockIdx.x * 256 + threadIdx.x;
  if (i < total) out[i] = bias[i & (OUT_F - 1)];
}

// ---------------- K3: scatter-add edges ------------------------------------
// 64 lanes (1 wave) per edge; lane handles channels {2l, 2l+1} via float2.
__global__ __launch_bounds__(256) void spmm_scatter(const int* __restrict__ erow,
                                                    const int* __restrict__ ecol,
                                                    const float* __restrict__ eval,
                                                    const float* __restrict__ sup,
                                                    float* __restrict__ out,
                                                    int n_edges) {
  long long t = (long long)blockIdx.x * 256 + threadIdx.x;
  int e = (int)(t >> 6);
  if (e >= n_edges) return;
  int lane = (int)(t & 63);
  int r = erow[e];
  int c = ecol[e];
  float v = eval[e];
  float2 s = ((const float2*)(sup + (size_t)c * OUT_F))[lane];
  float* orow = out + (size_t)r * OUT_F + 2 * lane;
  unsafeAtomicAdd(orow + 0, s.x * v);
  unsafeAtomicAdd(orow + 1, s.y * v);
}

// ---------------- K4: in-place ReLU ----------------------------------------
__global__ __launch_bounds__(256) void relu_k(float* __restrict__ out, int total) {
  int i = blockIdx.x * 256 + threadIdx.x;
  if (i < total) out[i] = fmaxf(out[i], 0.f);
}

extern "C" void kernel_launch(void* const* d_in, const int* in_sizes, int n_in,
                              void* d_out, int out_size, void* d_ws, size_t ws_size,
                              hipStream_t stream) {
  const float* x = (const float*)d_in[0];
  const int* erow = (const int*)d_in[1];
  const int* ecol = (const int*)d_in[2];
  const float* eval = (const float*)d_in[3];
  const float* w = (const float*)d_in[4];
  const float* bias = (const float*)d_in[5];
  float* out = (float*)d_out;

  int n_nodes = in_sizes[0] / IN_F;   // 100000
  int n_edges = in_sizes[1];          // 3200000
  int total = n_nodes * OUT_F;        // 12.8M

  float* sup = (float*)d_ws;          // 51.2 MB scratch

  // K1: support = x @ W
  int gemm_blocks = (n_nodes + 15) / 16;
  gemm_xw<<<gemm_blocks, 256, 0, stream>>>(x, w, sup, n_nodes);

  // K2: out = bias (accumulation base)
  init_bias<<<(total + 255) / 256, 256, 0, stream>>>(out, bias, total);

  // K3: scatter-add all edges
  long long threads = (long long)n_edges * 64;
  int blocks = (int)((threads + 255) / 256);
  spmm_scatter<<<blocks, 256, 0, stream>>>(erow, ecol, eval, sup, out, n_edges);

  // K4: relu in place
  relu_k<<<(total + 255) / 256, 256, 0, stream>>>(out, total);
}

// Round 2
// 1003.447 us; speedup vs baseline: 2.7544x; 2.7544x over previous
//
#include <hip/hip_runtime.h>

#define IN_F 256
#define OUT_F 128

// ---------------- K1: support = x @ W  (fp32, register-blocked) -------------
__global__ __launch_bounds__(256) void gemm_xw(const float* __restrict__ x,
                                               const float* __restrict__ w,
                                               float* __restrict__ sup,
                                               int n_nodes) {
  __shared__ float xs[16][IN_F];
  int row0 = blockIdx.x * 16;
  const float4* xg = (const float4*)(x + (size_t)row0 * IN_F);
  float4* xsv = (float4*)&xs[0][0];
#pragma unroll
  for (int i = 0; i < 4; ++i) xsv[threadIdx.x + i * 256] = xg[threadIdx.x + i * 256];
  __syncthreads();

  int c = threadIdx.x & 127;
  int rbase = (threadIdx.x >> 7) * 8;
  float acc[8] = {0.f, 0.f, 0.f, 0.f, 0.f, 0.f, 0.f, 0.f};
  for (int k = 0; k < IN_F; k += 4) {
    float w0 = w[(k + 0) * OUT_F + c];
    float w1 = w[(k + 1) * OUT_F + c];
    float w2 = w[(k + 2) * OUT_F + c];
    float w3 = w[(k + 3) * OUT_F + c];
#pragma unroll
    for (int r = 0; r < 8; ++r) {
      float4 xv = *(const float4*)&xs[rbase + r][k];
      acc[r] = fmaf(xv.x, w0, acc[r]);
      acc[r] = fmaf(xv.y, w1, acc[r]);
      acc[r] = fmaf(xv.z, w2, acc[r]);
      acc[r] = fmaf(xv.w, w3, acc[r]);
    }
  }
#pragma unroll
  for (int r = 0; r < 8; ++r) {
    int row = row0 + rbase + r;
    if (row < n_nodes) sup[(size_t)row * OUT_F + c] = acc[r];
  }
}

// ---------------- CSR build --------------------------------------------------
__global__ __launch_bounds__(256) void zero_counts(int* __restrict__ counts, int n) {
  int i = blockIdx.x * 256 + threadIdx.x;
  if (i < n) counts[i] = 0;
}

__global__ __launch_bounds__(256) void hist_rows(const int* __restrict__ erow,
                                                 int* __restrict__ counts, int n_edges) {
  int e = blockIdx.x * 256 + threadIdx.x;
  if (e < n_edges) atomicAdd(&counts[erow[e]], 1);
}

// single-block exclusive scan: row_ptr[i] = prefix, cursor[i] = prefix,
// row_ptr[n] = total. 1024 threads, each owns a contiguous chunk.
__global__ __launch_bounds__(1024) void scan_rowptr(const int* __restrict__ counts,
                                                    int* __restrict__ row_ptr,
                                                    int* __restrict__ cursor,
                                                    int n, int chunk) {
  __shared__ int part[1024];
  int t = threadIdx.x;
  int beg = t * chunk;
  int end = min(beg + chunk, n);
  int sum = 0;
  for (int i = beg; i < end; ++i) sum += counts[i];
  part[t] = sum;
  __syncthreads();
  for (int off = 1; off < 1024; off <<= 1) {
    int v = (t >= off) ? part[t - off] : 0;
    __syncthreads();
    part[t] += v;
    __syncthreads();
  }
  int run = part[t] - sum;  // exclusive base for this chunk
  for (int i = beg; i < end; ++i) {
    row_ptr[i] = run;
    cursor[i] = run;
    run += counts[i];
  }
  if (t == 1023) row_ptr[n] = part[1023];
}

__global__ __launch_bounds__(256) void scatter_perm(const int* __restrict__ erow,
                                                    const int* __restrict__ ecol,
                                                    const float* __restrict__ eval,
                                                    int* __restrict__ cursor,
                                                    int* __restrict__ pcol,
                                                    float* __restrict__ pval,
                                                    int n_edges) {
  int e = blockIdx.x * 256 + threadIdx.x;
  if (e >= n_edges) return;
  int r = erow[e];
  int pos = atomicAdd(&cursor[r], 1);
  pcol[pos] = ecol[e];
  pval[pos] = eval[e];
}

// ---------------- gather: out[r] = relu(bias + sum_j val*sup[col]) ----------
// one wave per row; lane owns channels {2l, 2l+1}.
__global__ __launch_bounds__(256) void spmm_gather(const int* __restrict__ row_ptr,
                                                   const int* __restrict__ pcol,
                                                   const float* __restrict__ pval,
                                                   const float* __restrict__ sup,
                                                   const float* __restrict__ bias,
                                                   float* __restrict__ out,
                                                   int n_nodes) {
  int r = blockIdx.x * 4 + (threadIdx.x >> 6);
  if (r >= n_nodes) return;
  int lane = threadIdx.x & 63;
  int beg = row_ptr[r];
  int end = row_ptr[r + 1];
  float ax = 0.f, ay = 0.f;
  for (int j = beg; j < end; ++j) {
    int c = pcol[j];
    float v = pval[j];
    float2 s = ((const float2*)(sup + (size_t)c * OUT_F))[lane];
    ax = fmaf(s.x, v, ax);
    ay = fmaf(s.y, v, ay);
  }
  float2 b = ((const float2*)bias)[lane];
  float2 o;
  o.x = fmaxf(ax + b.x, 0.f);
  o.y = fmaxf(ay + b.y, 0.f);
  ((float2*)(out + (size_t)r * OUT_F))[lane] = o;
}

// ---------------- fallback path (atomic scatter), used if ws too small ------
__global__ __launch_bounds__(256) void init_bias(float* __restrict__ out,
                                                 const float* __restrict__ bias,
                                                 int total) {
  int i = blockIdx.x * 256 + threadIdx.x;
  if (i < total) out[i] = bias[i & (OUT_F - 1)];
}

__global__ __launch_bounds__(256) void spmm_scatter(const int* __restrict__ erow,
                                                    const int* __restrict__ ecol,
                                                    const float* __restrict__ eval,
                                                    const float* __restrict__ sup,
                                                    float* __restrict__ out,
                                                    int n_edges) {
  long long t = (long long)blockIdx.x * 256 + threadIdx.x;
  int e = (int)(t >> 6);
  if (e >= n_edges) return;
  int lane = (int)(t & 63);
  int r = erow[e];
  int c = ecol[e];
  float v = eval[e];
  float2 s = ((const float2*)(sup + (size_t)c * OUT_F))[lane];
  float* orow = out + (size_t)r * OUT_F + 2 * lane;
  unsafeAtomicAdd(orow + 0, s.x * v);
  unsafeAtomicAdd(orow + 1, s.y * v);
}

__global__ __launch_bounds__(256) void relu_k(float* __restrict__ out, int total) {
  int i = blockIdx.x * 256 + threadIdx.x;
  if (i < total) out[i] = fmaxf(out[i], 0.f);
}

extern "C" void kernel_launch(void* const* d_in, const int* in_sizes, int n_in,
                              void* d_out, int out_size, void* d_ws, size_t ws_size,
                              hipStream_t stream) {
  const float* x = (const float*)d_in[0];
  const int* erow = (const int*)d_in[1];
  const int* ecol = (const int*)d_in[2];
  const float* eval = (const float*)d_in[3];
  const float* w = (const float*)d_in[4];
  const float* bias = (const float*)d_in[5];
  float* out = (float*)d_out;

  int n_nodes = in_sizes[0] / IN_F;   // 100000
  int n_edges = in_sizes[1];          // 3200000
  int total = n_nodes * OUT_F;

  // ws layout
  char* p = (char*)d_ws;
  float* sup = (float*)p;               p += (size_t)n_nodes * OUT_F * 4;
  int* pcol = (int*)p;                  p += (size_t)n_edges * 4;
  float* pval = (float*)p;              p += (size_t)n_edges * 4;
  int* counts = (int*)p;                p += (size_t)n_nodes * 4;
  int* row_ptr = (int*)p;               p += (size_t)(n_nodes + 1) * 4;
  int* cursor = (int*)p;                p += (size_t)n_nodes * 4;
  size_t need = (size_t)(p - (char*)d_ws);

  // K1: support = x @ W
  gemm_xw<<<(n_nodes + 15) / 16, 256, 0, stream>>>(x, w, sup, n_nodes);

  if (ws_size >= need) {
    // CSR build
    zero_counts<<<(n_nodes + 255) / 256, 256, 0, stream>>>(counts, n_nodes);
    hist_rows<<<(n_edges + 255) / 256, 256, 0, stream>>>(erow, counts, n_edges);
    int chunk = (n_nodes + 1023) / 1024;
    scan_rowptr<<<1, 1024, 0, stream>>>(counts, row_ptr, cursor, n_nodes, chunk);
    scatter_perm<<<(n_edges + 255) / 256, 256, 0, stream>>>(erow, ecol, eval, cursor,
                                                            pcol, pval, n_edges);
    // gather + bias + relu fused
    spmm_gather<<<(n_nodes + 3) / 4, 256, 0, stream>>>(row_ptr, pcol, pval, sup,
                                                       bias, out, n_nodes);
  } else {
    // fallback: atomic scatter path
    init_bias<<<(total + 255) / 256, 256, 0, stream>>>(out, bias, total);
    long long threads = (long long)n_edges * 64;
    spmm_scatter<<<(int)((threads + 255) / 256), 256, 0, stream>>>(erow, ecol, eval,
                                                                   sup, out, n_edges);
    relu_k<<<(total + 255) / 256, 256, 0, stream>>>(out, total);
  }
}

// Round 3
// 683.987 us; speedup vs baseline: 4.0409x; 1.4671x over previous
//
#include <hip/hip_runtime.h>
#include <hip/hip_fp16.h>

#define IN_F 256
#define OUT_F 128

// ---------------- K1: sup(fp16) = x @ W  (fp32 accum) -----------------------
__global__ __launch_bounds__(256) void gemm_xw(const float* __restrict__ x,
                                               const float* __restrict__ w,
                                               __half* __restrict__ sup,
                                               int n_nodes) {
  __shared__ float xs[16][IN_F];
  int row0 = blockIdx.x * 16;
  const float4* xg = (const float4*)(x + (size_t)row0 * IN_F);
  float4* xsv = (float4*)&xs[0][0];
#pragma unroll
  for (int i = 0; i < 4; ++i) xsv[threadIdx.x + i * 256] = xg[threadIdx.x + i * 256];
  __syncthreads();

  int c = threadIdx.x & 127;
  int rbase = (threadIdx.x >> 7) * 8;
  float acc[8] = {0.f, 0.f, 0.f, 0.f, 0.f, 0.f, 0.f, 0.f};
  for (int k = 0; k < IN_F; k += 4) {
    float w0 = w[(k + 0) * OUT_F + c];
    float w1 = w[(k + 1) * OUT_F + c];
    float w2 = w[(k + 2) * OUT_F + c];
    float w3 = w[(k + 3) * OUT_F + c];
#pragma unroll
    for (int r = 0; r < 8; ++r) {
      float4 xv = *(const float4*)&xs[rbase + r][k];
      acc[r] = fmaf(xv.x, w0, acc[r]);
      acc[r] = fmaf(xv.y, w1, acc[r]);
      acc[r] = fmaf(xv.z, w2, acc[r]);
      acc[r] = fmaf(xv.w, w3, acc[r]);
    }
  }
#pragma unroll
  for (int r = 0; r < 8; ++r) {
    int row = row0 + rbase + r;
    if (row < n_nodes) sup[(size_t)row * OUT_F + c] = __float2half(acc[r]);
  }
}

// ---------------- CSR build --------------------------------------------------
__global__ __launch_bounds__(256) void zero_counts(int* __restrict__ counts, int n) {
  int i = blockIdx.x * 256 + threadIdx.x;
  if (i < n) counts[i] = 0;
}

__global__ __launch_bounds__(256) void hist_rows(const int* __restrict__ erow,
                                                 int* __restrict__ counts, int n_edges) {
  int e = blockIdx.x * 256 + threadIdx.x;
  if (e < n_edges) atomicAdd(&counts[erow[e]], 1);
}

// S1: per-1024-chunk partial sums
__global__ __launch_bounds__(256) void scan_part(const int* __restrict__ counts,
                                                 int* __restrict__ partials, int n) {
  __shared__ int red[256];
  int base = blockIdx.x * 1024;
  int t = threadIdx.x;
  int s = 0;
#pragma unroll
  for (int i = 0; i < 4; ++i) {
    int idx = base + 4 * t + i;  // thread t owns 4 consecutive
    if (idx < n) s += counts[idx];
  }
  red[t] = s;
  __syncthreads();
  for (int off = 128; off > 0; off >>= 1) {
    if (t < off) red[t] += red[t + off];
    __syncthreads();
  }
  if (t == 0) partials[blockIdx.x] = red[0];
}

// S2: exclusive-scan the nb partials (nb <= 256); partials[nb] = total
__global__ __launch_bounds__(256) void scan_partials(int* __restrict__ partials, int nb) {
  __shared__ int tmp[256];
  int t = threadIdx.x;
  int v = (t < nb) ? partials[t] : 0;
  tmp[t] = v;
  __syncthreads();
  for (int off = 1; off < 256; off <<= 1) {
    int u = (t >= off) ? tmp[t - off] : 0;
    __syncthreads();
    tmp[t] += u;
    __syncthreads();
  }
  if (t < nb) partials[t] = tmp[t] - v;       // exclusive base per chunk
  if (t == 0) partials[nb] = tmp[255];        // grand total
}

// S3: per-chunk exclusive scan + write row_ptr & cursor
__global__ __launch_bounds__(256) void scan_write(const int* __restrict__ counts,
                                                  const int* __restrict__ partials,
                                                  int* __restrict__ row_ptr,
                                                  int* __restrict__ cursor,
                                                  int n, int nb) {
  __shared__ int tmp[256];
  int base = blockIdx.x * 1024;
  int t = threadIdx.x;
  int idx0 = base + 4 * t;
  int c0 = (idx0 + 0 < n) ? counts[idx0 + 0] : 0;
  int c1 = (idx0 + 1 < n) ? counts[idx0 + 1] : 0;
  int c2 = (idx0 + 2 < n) ? counts[idx0 + 2] : 0;
  int c3 = (idx0 + 3 < n) ? counts[idx0 + 3] : 0;
  int s = c0 + c1 + c2 + c3;
  tmp[t] = s;
  __syncthreads();
  for (int off = 1; off < 256; off <<= 1) {
    int u = (t >= off) ? tmp[t - off] : 0;
    __syncthreads();
    tmp[t] += u;
    __syncthreads();
  }
  int run = tmp[t] - s + partials[blockIdx.x];
  if (idx0 + 0 < n) { row_ptr[idx0 + 0] = run; cursor[idx0 + 0] = run; run += c0; }
  if (idx0 + 1 < n) { row_ptr[idx0 + 1] = run; cursor[idx0 + 1] = run; run += c1; }
  if (idx0 + 2 < n) { row_ptr[idx0 + 2] = run; cursor[idx0 + 2] = run; run += c2; }
  if (idx0 + 3 < n) { row_ptr[idx0 + 3] = run; cursor[idx0 + 3] = run; run += c3; }
  if (blockIdx.x == 0 && t == 0) row_ptr[n] = partials[nb];
}

// permute edges into row-sorted packed CSR: pedge[pos] = {col, val_bits}
__global__ __launch_bounds__(256) void scatter_perm(const int* __restrict__ erow,
                                                    const int* __restrict__ ecol,
                                                    const float* __restrict__ eval,
                                                    int* __restrict__ cursor,
                                                    int2* __restrict__ pedge,
                                                    int n_edges) {
  int e = blockIdx.x * 256 + threadIdx.x;
  if (e >= n_edges) return;
  int r = erow[e];
  int pos = atomicAdd(&cursor[r], 1);
  int2 pk;
  pk.x = ecol[e];
  pk.y = __float_as_int(eval[e]);
  pedge[pos] = pk;
}

// ---------------- gather: out[r] = relu(bias + sum_j val*sup[col]) ----------
__global__ __launch_bounds__(256) void spmm_gather(const int* __restrict__ row_ptr,
                                                   const int2* __restrict__ pedge,
                                                   const __half* __restrict__ sup,
                                                   const float* __restrict__ bias,
                                                   float* __restrict__ out,
                                                   int n_nodes) {
  int r = blockIdx.x * 4 + (threadIdx.x >> 6);
  if (r >= n_nodes) return;
  int lane = threadIdx.x & 63;
  int beg = row_ptr[r];
  int end = row_ptr[r + 1];
  float ax = 0.f, ay = 0.f, bx = 0.f, by = 0.f;
  int j = beg;
  for (; j + 1 < end; j += 2) {
    int2 e0 = pedge[j];
    int2 e1 = pedge[j + 1];
    __half2 s0 = ((const __half2*)(sup + (size_t)e0.x * OUT_F))[lane];
    __half2 s1 = ((const __half2*)(sup + (size_t)e1.x * OUT_F))[lane];
    float v0 = __int_as_float(e0.y);
    float v1 = __int_as_float(e1.y);
    float2 f0 = __half22float2(s0);
    float2 f1 = __half22float2(s1);
    ax = fmaf(f0.x, v0, ax);
    ay = fmaf(f0.y, v0, ay);
    bx = fmaf(f1.x, v1, bx);
    by = fmaf(f1.y, v1, by);
  }
  if (j < end) {
    int2 e0 = pedge[j];
    __half2 s0 = ((const __half2*)(sup + (size_t)e0.x * OUT_F))[lane];
    float v0 = __int_as_float(e0.y);
    float2 f0 = __half22float2(s0);
    ax = fmaf(f0.x, v0, ax);
    ay = fmaf(f0.y, v0, ay);
  }
  ax += bx;
  ay += by;
  float2 b = ((const float2*)bias)[lane];
  float2 o;
  o.x = fmaxf(ax + b.x, 0.f);
  o.y = fmaxf(ay + b.y, 0.f);
  ((float2*)(out + (size_t)r * OUT_F))[lane] = o;
}

// ---------------- fallback (atomic scatter) ---------------------------------
__global__ __launch_bounds__(256) void init_bias(float* __restrict__ out,
                                                 const float* __restrict__ bias,
                                                 int total) {
  int i = blockIdx.x * 256 + threadIdx.x;
  if (i < total) out[i] = bias[i & (OUT_F - 1)];
}

__global__ __launch_bounds__(256) void spmm_scatter(const int* __restrict__ erow,
                                                    const int* __restrict__ ecol,
                                                    const float* __restrict__ eval,
                                                    const __half* __restrict__ sup,
                                                    float* __restrict__ out,
                                                    int n_edges) {
  long long t = (long long)blockIdx.x * 256 + threadIdx.x;
  int e = (int)(t >> 6);
  if (e >= n_edges) return;
  int lane = (int)(t & 63);
  int r = erow[e];
  int c = ecol[e];
  float v = eval[e];
  __half2 s = ((const __half2*)(sup + (size_t)c * OUT_F))[lane];
  float2 f = __half22float2(s);
  float* orow = out + (size_t)r * OUT_F + 2 * lane;
  unsafeAtomicAdd(orow + 0, f.x * v);
  unsafeAtomicAdd(orow + 1, f.y * v);
}

__global__ __launch_bounds__(256) void relu_k(float* __restrict__ out, int total) {
  int i = blockIdx.x * 256 + threadIdx.x;
  if (i < total) out[i] = fmaxf(out[i], 0.f);
}

// single-block scan fallback (only if n > 256*1024)
__global__ __launch_bounds__(1024) void scan_rowptr(const int* __restrict__ counts,
                                                    int* __restrict__ row_ptr,
                                                    int* __restrict__ cursor,
                                                    int n, int chunk) {
  __shared__ int part[1024];
  int t = threadIdx.x;
  int beg = t * chunk;
  int end = min(beg + chunk, n);
  int sum = 0;
  for (int i = beg; i < end; ++i) sum += counts[i];
  part[t] = sum;
  __syncthreads();
  for (int off = 1; off < 1024; off <<= 1) {
    int v = (t >= off) ? part[t - off] : 0;
    __syncthreads();
    part[t] += v;
    __syncthreads();
  }
  int run = part[t] - sum;
  for (int i = beg; i < end; ++i) {
    row_ptr[i] = run;
    cursor[i] = run;
    run += counts[i];
  }
  if (t == 1023) row_ptr[n] = part[1023];
}

extern "C" void kernel_launch(void* const* d_in, const int* in_sizes, int n_in,
                              void* d_out, int out_size, void* d_ws, size_t ws_size,
                              hipStream_t stream) {
  const float* x = (const float*)d_in[0];
  const int* erow = (const int*)d_in[1];
  const int* ecol = (const int*)d_in[2];
  const float* eval = (const float*)d_in[3];
  const float* w = (const float*)d_in[4];
  const float* bias = (const float*)d_in[5];
  float* out = (float*)d_out;

  int n_nodes = in_sizes[0] / IN_F;   // 100000
  int n_edges = in_sizes[1];          // 3200000
  int total = n_nodes * OUT_F;

  // ws layout
  char* p = (char*)d_ws;
  __half* sup = (__half*)p;             p += (size_t)n_nodes * OUT_F * 2;
  int2* pedge = (int2*)p;               p += (size_t)n_edges * 8;
  int* counts = (int*)p;                p += (size_t)n_nodes * 4;
  int* row_ptr = (int*)p;               p += (size_t)(n_nodes + 1) * 4;
  int* cursor = (int*)p;                p += (size_t)n_nodes * 4;
  int* partials = (int*)p;              p += (size_t)260 * 4;
  size_t need = (size_t)(p - (char*)d_ws);

  // K1: support = x @ W  (fp16 out)
  gemm_xw<<<(n_nodes + 15) / 16, 256, 0, stream>>>(x, w, sup, n_nodes);

  if (ws_size >= need) {
    zero_counts<<<(n_nodes + 255) / 256, 256, 0, stream>>>(counts, n_nodes);
    hist_rows<<<(n_edges + 255) / 256, 256, 0, stream>>>(erow, counts, n_edges);
    int nb = (n_nodes + 1023) / 1024;
    if (nb <= 256) {
      scan_part<<<nb, 256, 0, stream>>>(counts, partials, n_nodes);
      scan_partials<<<1, 256, 0, stream>>>(partials, nb);
      scan_write<<<nb, 256, 0, stream>>>(counts, partials, row_ptr, cursor,
                                         n_nodes, nb);
    } else {
      int chunk = (n_nodes + 1023) / 1024;
      scan_rowptr<<<1, 1024, 0, stream>>>(counts, row_ptr, cursor, n_nodes, chunk);
    }
    scatter_perm<<<(n_edges + 255) / 256, 256, 0, stream>>>(erow, ecol, eval, cursor,
                                                            pedge, n_edges);
    spmm_gather<<<(n_nodes + 3) / 4, 256, 0, stream>>>(row_ptr, pedge, sup,
                                                       bias, out, n_nodes);
  } else {
    init_bias<<<(total + 255) / 256, 256, 0, stream>>>(out, bias, total);
    long long threads = (long long)n_edges * 64;
    spmm_scatter<<<(int)((threads + 255) / 256), 256, 0, stream>>>(erow, ecol, eval,
                                                                   sup, out, n_edges);
    relu_k<<<(total + 255) / 256, 256, 0, stream>>>(out, total);
  }
}